// Round 1
// baseline (863.674 us; speedup 1.0000x reference)
//
#include <hip/hip_runtime.h>
#include <math.h>

// Fused dual-LeNet + len-19 full convolution + log.
// One block per sample; 256 threads; threads [0,128) process channel 0,
// [128,256) process channel 1. All intermediates in LDS.

__global__ __launch_bounds__(256) void lenet_fused(
    const float* __restrict__ x,     // [B,2,28,28]
    const float* __restrict__ cw1,   // [6,1,5,5]
    const float* __restrict__ cb1,   // [6]
    const float* __restrict__ cw2,   // [16,6,5,5]
    const float* __restrict__ cb2,   // [16]
    const float* __restrict__ fw1,   // [120,256]
    const float* __restrict__ fb1,   // [120]
    const float* __restrict__ fw2,   // [84,120]
    const float* __restrict__ fb2,   // [84]
    const float* __restrict__ fw3,   // [10,84]
    const float* __restrict__ fb3,   // [10]
    float* __restrict__ out)         // [B,19]
{
    const int b  = blockIdx.x;
    const int tid = threadIdx.x;
    const int ch = tid >> 7;        // 0 or 1
    const int lt = tid & 127;       // lane within channel-half

    __shared__ float s_img [2][28*28];     // input image
    __shared__ float s_p1  [2][6*12*12];   // relu(pool(conv1))
    __shared__ float s_p2  [2][256];       // relu(pool(conv2)) flattened
    __shared__ float s_f1  [2][120];
    __shared__ float s_f2  [2][84];
    __shared__ float s_log [2][10];        // fc3 logits
    __shared__ float s_prob[2][10];        // softmax probs

    // ---- load image ----
    const float* xb = x + ((size_t)b * 2 + ch) * 784;
    for (int i = lt; i < 784; i += 128) s_img[ch][i] = xb[i];
    __syncthreads();

    // ---- conv1 (5x5, 1->6) + maxpool2x2 + relu : 6*12*12 = 864 outputs ----
    for (int i = lt; i < 864; i += 128) {
        int o  = i / 144;
        int r  = i - o * 144;
        int py = r / 12;
        int px = r - py * 12;
        const float* w    = cw1 + o * 25;
        const float* base = &s_img[ch][(py * 2) * 28 + px * 2];
        float a00 = 0.f, a01 = 0.f, a10 = 0.f, a11 = 0.f;
#pragma unroll
        for (int ky = 0; ky < 5; ++ky) {
#pragma unroll
            for (int kx = 0; kx < 5; ++kx) {
                float wv = w[ky * 5 + kx];
                const float* p = base + ky * 28 + kx;
                a00 += p[0]  * wv;
                a01 += p[1]  * wv;
                a10 += p[28] * wv;
                a11 += p[29] * wv;
            }
        }
        float m = fmaxf(fmaxf(a00, a01), fmaxf(a10, a11)) + cb1[o];
        s_p1[ch][i] = fmaxf(m, 0.f);
    }
    __syncthreads();

    // ---- conv2 (5x5, 6->16) + maxpool2x2 + relu : 16*4*4 = 256 outputs ----
    for (int i = lt; i < 256; i += 128) {
        int o  = i >> 4;
        int py = (i >> 2) & 3;
        int px = i & 3;
        const float* w = cw2 + o * 150;
        float a00 = 0.f, a01 = 0.f, a10 = 0.f, a11 = 0.f;
        for (int ic = 0; ic < 6; ++ic) {
            const float* wi   = w + ic * 25;
            const float* base = &s_p1[ch][ic * 144 + (py * 2) * 12 + px * 2];
#pragma unroll
            for (int ky = 0; ky < 5; ++ky) {
#pragma unroll
                for (int kx = 0; kx < 5; ++kx) {
                    float wv = wi[ky * 5 + kx];
                    const float* p = base + ky * 12 + kx;
                    a00 += p[0]  * wv;
                    a01 += p[1]  * wv;
                    a10 += p[12] * wv;
                    a11 += p[13] * wv;
                }
            }
        }
        float m = fmaxf(fmaxf(a00, a01), fmaxf(a10, a11)) + cb2[o];
        s_p2[ch][i] = fmaxf(m, 0.f);   // flatten order o*16 + y*4 + x  ✓ reshape
    }
    __syncthreads();

    // ---- fc1: 256 -> 120, relu ----
    if (lt < 120) {
        const float4* wr = (const float4*)(fw1 + lt * 256);
        float s = 0.f;
#pragma unroll 4
        for (int k4 = 0; k4 < 64; ++k4) {
            float4 w4 = wr[k4];
            const float* pv = &s_p2[ch][k4 * 4];
            s += w4.x * pv[0] + w4.y * pv[1] + w4.z * pv[2] + w4.w * pv[3];
        }
        s_f1[ch][lt] = fmaxf(s + fb1[lt], 0.f);
    }
    __syncthreads();

    // ---- fc2: 120 -> 84, relu ----
    if (lt < 84) {
        const float4* wr = (const float4*)(fw2 + lt * 120);
        float s = 0.f;
#pragma unroll 5
        for (int k4 = 0; k4 < 30; ++k4) {
            float4 w4 = wr[k4];
            const float* pv = &s_f1[ch][k4 * 4];
            s += w4.x * pv[0] + w4.y * pv[1] + w4.z * pv[2] + w4.w * pv[3];
        }
        s_f2[ch][lt] = fmaxf(s + fb2[lt], 0.f);
    }
    __syncthreads();

    // ---- fc3: 84 -> 10 (logits) ----
    if (lt < 10) {
        const float4* wr = (const float4*)(fw3 + lt * 84);
        float s = 0.f;
#pragma unroll
        for (int k4 = 0; k4 < 21; ++k4) {
            float4 w4 = wr[k4];
            const float* pv = &s_f2[ch][k4 * 4];
            s += w4.x * pv[0] + w4.y * pv[1] + w4.z * pv[2] + w4.w * pv[3];
        }
        s_log[ch][lt] = s + fb3[lt];
    }
    __syncthreads();

    // ---- softmax (serial per channel; 10 elements) ----
    if (lt == 0) {
        float mx = s_log[ch][0];
        for (int j = 1; j < 10; ++j) mx = fmaxf(mx, s_log[ch][j]);
        float e[10];
        float sum = 0.f;
        for (int j = 0; j < 10; ++j) { e[j] = expf(s_log[ch][j] - mx); sum += e[j]; }
        float inv = 1.f / sum;
        for (int j = 0; j < 10; ++j) s_prob[ch][j] = e[j] * inv;
    }
    __syncthreads();

    // ---- full convolution of the two prob vectors (len 19) + log ----
    if (tid < 19) {
        int t = tid;
        int jlo = t - 9 > 0 ? t - 9 : 0;
        int jhi = t < 9 ? t : 9;
        float z = 0.f;
        for (int j = jlo; j <= jhi; ++j)
            z += s_prob[0][j] * s_prob[1][t - j];
        out[(size_t)b * 19 + t] = logf(z);
    }
}

extern "C" void kernel_launch(void* const* d_in, const int* in_sizes, int n_in,
                              void* d_out, int out_size, void* d_ws, size_t ws_size,
                              hipStream_t stream) {
    const float* x   = (const float*)d_in[0];
    const float* cw1 = (const float*)d_in[1];
    const float* cb1 = (const float*)d_in[2];
    const float* cw2 = (const float*)d_in[3];
    const float* cb2 = (const float*)d_in[4];
    const float* fw1 = (const float*)d_in[5];
    const float* fb1 = (const float*)d_in[6];
    const float* fw2 = (const float*)d_in[7];
    const float* fb2 = (const float*)d_in[8];
    const float* fw3 = (const float*)d_in[9];
    const float* fb3 = (const float*)d_in[10];
    float* out = (float*)d_out;

    const int B = in_sizes[0] / (2 * 28 * 28);   // 16384

    lenet_fused<<<B, 256, 0, stream>>>(x, cw1, cb1, cw2, cb2,
                                       fw1, fb1, fw2, fb2, fw3, fb3, out);
}

// Round 2
// 794.049 us; speedup vs baseline: 1.0877x; 1.0877x over previous
//
#include <hip/hip_runtime.h>
#include <math.h>

// Fused dual-LeNet + len-19 full convolution + log.
// One block per sample; 256 threads shared across both channels per phase.
// Convs are register-blocked: aligned b128 LDS patch loads, FMAs from regs.

__global__ __launch_bounds__(256) void lenet_fused(
    const float* __restrict__ x,     // [B,2,28,28]
    const float* __restrict__ cw1,   // [6,1,5,5]
    const float* __restrict__ cb1,   // [6]
    const float* __restrict__ cw2,   // [16,6,5,5]
    const float* __restrict__ cb2,   // [16]
    const float* __restrict__ fw1,   // [120,256]
    const float* __restrict__ fb1,   // [120]
    const float* __restrict__ fw2,   // [84,120]
    const float* __restrict__ fb2,   // [84]
    const float* __restrict__ fw3,   // [10,84]
    const float* __restrict__ fb3,   // [10]
    float* __restrict__ out)         // [B,19]
{
    const int b   = blockIdx.x;
    const int tid = threadIdx.x;

    __shared__ __align__(16) float s_img [2*784];   // input, both channels
    __shared__ __align__(16) float s_p1  [2*864];   // relu(pool(conv1)) [ch][6][12][12]
    __shared__ __align__(16) float s_p2  [2*256];   // relu(pool(conv2)) flat [ch][16*4*4]
    __shared__ __align__(16) float s_f1  [2*120];
    __shared__ __align__(16) float s_f2  [2*84];
    __shared__ __align__(16) float s_log [2*10];
    __shared__ __align__(16) float s_prob[2*10];

    // ---- load image: 1568 floats = 392 float4, fully coalesced ----
    {
        const float4* xb  = (const float4*)(x + (size_t)b * 1568);
        float4*       si4 = (float4*)s_img;
        for (int i = tid; i < 392; i += 256) si4[i] = xb[i];
    }
    __syncthreads();

    // ---- conv1 5x5 (1->6) + pool2x2 + relu ----
    // task t: o fastest (o not in LDS address -> 6-lane broadcast groups)
    // t -> (ch, py, g, o); each task: 4 pool outputs px = 4g..4g+3
    for (int t = tid; t < 432; t += 256) {
        int o  = t % 6;
        int u  = t / 6;
        int g  = u % 3;
        int v  = u / 3;
        int py = v % 12;
        int ch = v / 12;

        float w[25];
#pragma unroll
        for (int k = 0; k < 25; ++k) w[k] = cw1[o * 25 + k];

        float acc0[8], acc1[8];
#pragma unroll
        for (int i = 0; i < 8; ++i) { acc0[i] = 0.f; acc1[i] = 0.f; }

        const float* srow = &s_img[ch * 784 + (py * 2) * 28 + g * 8];
#pragma unroll
        for (int r = 0; r < 6; ++r) {
            const float4* rp = (const float4*)(srow + r * 28);  // 16B aligned
            float4 q0 = rp[0], q1 = rp[1], q2 = rp[2];
            float row[12] = {q0.x,q0.y,q0.z,q0.w,q1.x,q1.y,q1.z,q1.w,q2.x,q2.y,q2.z,q2.w};
            if (r <= 4) {
#pragma unroll
                for (int kx = 0; kx < 5; ++kx)
#pragma unroll
                    for (int cc = 0; cc < 8; ++cc)
                        acc0[cc] = fmaf(row[cc + kx], w[r * 5 + kx], acc0[cc]);
            }
            if (r >= 1) {
#pragma unroll
                for (int kx = 0; kx < 5; ++kx)
#pragma unroll
                    for (int cc = 0; cc < 8; ++cc)
                        acc1[cc] = fmaf(row[cc + kx], w[(r - 1) * 5 + kx], acc1[cc]);
            }
        }
        float bsum = cb1[o];
#pragma unroll
        for (int j = 0; j < 4; ++j) {
            float m = fmaxf(fmaxf(acc0[2*j], acc0[2*j+1]), fmaxf(acc1[2*j], acc1[2*j+1]));
            s_p1[ch * 864 + o * 144 + py * 12 + g * 4 + j] = fmaxf(m + bsum, 0.f);
        }
    }
    __syncthreads();

    // ---- conv2 5x5 (6->16) + pool2x2 + relu : exactly 256 tasks, 1 round ----
    // t = ((py*2+pxp)*2 + ch)*16 + o ; each task: 2 pool outputs px = 2*pxp..2*pxp+1
    {
        int t   = tid;
        int o   = t & 15;
        int u   = t >> 4;
        int ch  = u & 1;
        int pp  = u >> 1;
        int py  = pp >> 1;
        int pxp = pp & 1;

        float acc0[4], acc1[4];
#pragma unroll
        for (int i = 0; i < 4; ++i) { acc0[i] = 0.f; acc1[i] = 0.f; }

        const float* pbase = &s_p1[ch * 864 + (py * 2) * 12 + pxp * 4];
        const float* wbase = cw2 + o * 150;

        for (int ic = 0; ic < 6; ++ic) {
            float w[25];
#pragma unroll
            for (int k = 0; k < 25; ++k) w[k] = wbase[ic * 25 + k];
            const float* prow = pbase + ic * 144;
#pragma unroll
            for (int r = 0; r < 6; ++r) {
                const float4* rp = (const float4*)(prow + r * 12);  // 16B aligned
                float4 q0 = rp[0], q1 = rp[1];
                float row[8] = {q0.x,q0.y,q0.z,q0.w,q1.x,q1.y,q1.z,q1.w};
                if (r <= 4) {
#pragma unroll
                    for (int kx = 0; kx < 5; ++kx)
#pragma unroll
                        for (int cc = 0; cc < 4; ++cc)
                            acc0[cc] = fmaf(row[cc + kx], w[r * 5 + kx], acc0[cc]);
                }
                if (r >= 1) {
#pragma unroll
                    for (int kx = 0; kx < 5; ++kx)
#pragma unroll
                        for (int cc = 0; cc < 4; ++cc)
                            acc1[cc] = fmaf(row[cc + kx], w[(r - 1) * 5 + kx], acc1[cc]);
                }
            }
        }
        float bsum = cb2[o];
#pragma unroll
        for (int j = 0; j < 2; ++j) {
            float m = fmaxf(fmaxf(acc0[2*j], acc0[2*j+1]), fmaxf(acc1[2*j], acc1[2*j+1]));
            s_p2[ch * 256 + o * 16 + py * 4 + (pxp * 2 + j)] = fmaxf(m + bsum, 0.f);
        }
    }
    __syncthreads();

    // ---- fc1: 256 -> 120, relu (240 tasks) ----
    if (tid < 240) {
        int ch = (tid >= 120) ? 1 : 0;
        int o  = tid - 120 * ch;
        const float4* wr = (const float4*)(fw1 + o * 256);
        const float4* pv = (const float4*)(&s_p2[ch * 256]);
        float s = 0.f;
#pragma unroll 8
        for (int k = 0; k < 64; ++k) {
            float4 w4 = wr[k], p4 = pv[k];
            s = fmaf(w4.x, p4.x, s); s = fmaf(w4.y, p4.y, s);
            s = fmaf(w4.z, p4.z, s); s = fmaf(w4.w, p4.w, s);
        }
        s_f1[ch * 120 + o] = fmaxf(s + fb1[o], 0.f);
    }
    __syncthreads();

    // ---- fc2: 120 -> 84, relu (168 tasks) ----
    if (tid < 168) {
        int ch = (tid >= 84) ? 1 : 0;
        int o  = tid - 84 * ch;
        const float4* wr = (const float4*)(fw2 + o * 120);
        const float4* pv = (const float4*)(&s_f1[ch * 120]);
        float s = 0.f;
#pragma unroll 6
        for (int k = 0; k < 30; ++k) {
            float4 w4 = wr[k], p4 = pv[k];
            s = fmaf(w4.x, p4.x, s); s = fmaf(w4.y, p4.y, s);
            s = fmaf(w4.z, p4.z, s); s = fmaf(w4.w, p4.w, s);
        }
        s_f2[ch * 84 + o] = fmaxf(s + fb2[o], 0.f);
    }
    __syncthreads();

    // ---- fc3: 84 -> 10 (20 tasks) ----
    if (tid < 20) {
        int ch = (tid >= 10) ? 1 : 0;
        int o  = tid - 10 * ch;
        const float4* wr = (const float4*)(fw3 + o * 84);
        const float4* pv = (const float4*)(&s_f2[ch * 84]);
        float s = 0.f;
#pragma unroll
        for (int k = 0; k < 21; ++k) {
            float4 w4 = wr[k], p4 = pv[k];
            s = fmaf(w4.x, p4.x, s); s = fmaf(w4.y, p4.y, s);
            s = fmaf(w4.z, p4.z, s); s = fmaf(w4.w, p4.w, s);
        }
        s_log[ch * 10 + o] = s + fb3[o];
    }
    __syncthreads();

    // ---- softmax per channel (2 lanes) ----
    if (tid < 2) {
        const float* lg = &s_log[tid * 10];
        float mx = lg[0];
#pragma unroll
        for (int j = 1; j < 10; ++j) mx = fmaxf(mx, lg[j]);
        float e[10], sum = 0.f;
#pragma unroll
        for (int j = 0; j < 10; ++j) { e[j] = expf(lg[j] - mx); sum += e[j]; }
        float inv = 1.f / sum;
#pragma unroll
        for (int j = 0; j < 10; ++j) s_prob[tid * 10 + j] = e[j] * inv;
    }
    __syncthreads();

    // ---- full convolution (len 19) + log ----
    if (tid < 19) {
        int t   = tid;
        int jlo = t - 9 > 0 ? t - 9 : 0;
        int jhi = t < 9 ? t : 9;
        float z = 0.f;
        for (int j = jlo; j <= jhi; ++j)
            z += s_prob[j] * s_prob[10 + (t - j)];
        out[(size_t)b * 19 + t] = logf(z);
    }
}

extern "C" void kernel_launch(void* const* d_in, const int* in_sizes, int n_in,
                              void* d_out, int out_size, void* d_ws, size_t ws_size,
                              hipStream_t stream) {
    const float* x   = (const float*)d_in[0];
    const float* cw1 = (const float*)d_in[1];
    const float* cb1 = (const float*)d_in[2];
    const float* cw2 = (const float*)d_in[3];
    const float* cb2 = (const float*)d_in[4];
    const float* fw1 = (const float*)d_in[5];
    const float* fb1 = (const float*)d_in[6];
    const float* fw2 = (const float*)d_in[7];
    const float* fb2 = (const float*)d_in[8];
    const float* fw3 = (const float*)d_in[9];
    const float* fb3 = (const float*)d_in[10];
    float* out = (float*)d_out;

    const int B = in_sizes[0] / (2 * 28 * 28);   // 16384

    lenet_fused<<<B, 256, 0, stream>>>(x, cw1, cb1, cw2, cb2,
                                       fw1, fb1, fw2, fb2, fw3, fb3, out);
}

// Round 3
// 572.405 us; speedup vs baseline: 1.5088x; 1.3872x over previous
//
#include <hip/hip_runtime.h>
#include <math.h>

// Fused dual-LeNet + len-19 full convolution + log.
// 2 samples (4 LeNet instances) per block, 256 threads.
// Conv weights staged in LDS (transposed, conflict-free broadcast reads);
// __launch_bounds__(256,4) gives the compiler 128 VGPRs for real ILP.

#define SPB 2   // samples per block

__global__ __launch_bounds__(256, 4) void lenet_fused(
    const float* __restrict__ x,     // [B,2,28,28]
    const float* __restrict__ cw1,   // [6,1,5,5]
    const float* __restrict__ cb1,   // [6]
    const float* __restrict__ cw2,   // [16,6,5,5]
    const float* __restrict__ cb2,   // [16]
    const float* __restrict__ fw1,   // [120,256]
    const float* __restrict__ fb1,   // [120]
    const float* __restrict__ fw2,   // [84,120]
    const float* __restrict__ fb2,   // [84]
    const float* __restrict__ fw3,   // [10,84]
    const float* __restrict__ fb3,   // [10]
    float* __restrict__ out)         // [B,19]
{
    const int tid = threadIdx.x;
    const int b0  = blockIdx.x * SPB;

    // s_pool holds the images; after conv1 the images are dead and the same
    // space is reused for p2 / f1 / f2 / logits / probs (phases separated by
    // barriers, reads/writes within a phase are disjoint).
    __shared__ __align__(16) float s_pool[4 * 784];      // 12.5 KB
    __shared__ __align__(16) float s_p1  [4 * 864];      // 13.8 KB [inst][6][12][12]
    __shared__ __align__(16) float s_w1t [25 * 8];       // conv1 W^T [k][o]
    __shared__ float s_b1[8];
    __shared__ __align__(16) float s_w2t [150 * 16];     // conv2 W^T [ic*25+k][o]
    __shared__ float s_b2[16];

    float* s_img  = s_pool;          // 3136 floats (4 inst x 784)
    float* s_p2   = s_pool;          // 1024
    float* s_f1   = s_pool + 1024;   // 480
    float* s_f2   = s_pool + 1504;   // 336
    float* s_log  = s_pool + 1840;   // 40
    float* s_prob = s_pool + 1880;   // 40

    // ---- stage images + conv weights ----
    {
        const float4* xb = (const float4*)(x + (size_t)b0 * 1568);
        float4* si = (float4*)s_img;
        for (int i = tid; i < 392 * SPB; i += 256) si[i] = xb[i];
    }
    for (int i = tid; i < 150; i += 256) {          // cw1 -> [k][o] (stride 8)
        int o = i / 25, k = i % 25;
        s_w1t[k * 8 + o] = cw1[i];
    }
    for (int i = tid; i < 2400; i += 256) {         // cw2 -> [ic*25+k][o] (stride 16)
        int o = i / 150, r = i % 150;
        s_w2t[r * 16 + o] = cw2[i];
    }
    if (tid < 6)  s_b1[tid] = cb1[tid];
    if (tid < 16) s_b2[tid] = cb2[tid];
    __syncthreads();

    // ---- conv1 5x5 (1->6) + pool2x2 + relu : 864 tasks ----
    // t -> o fastest (weight broadcast groups), then g, py, inst
    for (int t = tid; t < 864; t += 256) {
        int o  = t % 6;  int u = t / 6;
        int g  = u % 3;  u /= 3;
        int py = u % 12; int inst = u / 12;

        float w[25];
#pragma unroll
        for (int k = 0; k < 25; ++k) w[k] = s_w1t[k * 8 + o];

        float acc0[8], acc1[8];
#pragma unroll
        for (int i = 0; i < 8; ++i) { acc0[i] = 0.f; acc1[i] = 0.f; }

        const float* srow = &s_img[inst * 784 + (py * 2) * 28 + g * 8];
#pragma unroll
        for (int r = 0; r < 6; ++r) {
            const float4* rp = (const float4*)(srow + r * 28);  // 16B aligned
            float4 q0 = rp[0], q1 = rp[1], q2 = rp[2];
            float row[12] = {q0.x,q0.y,q0.z,q0.w,q1.x,q1.y,q1.z,q1.w,q2.x,q2.y,q2.z,q2.w};
            if (r <= 4) {
#pragma unroll
                for (int kx = 0; kx < 5; ++kx)
#pragma unroll
                    for (int cc = 0; cc < 8; ++cc)
                        acc0[cc] = fmaf(row[cc + kx], w[r * 5 + kx], acc0[cc]);
            }
            if (r >= 1) {
#pragma unroll
                for (int kx = 0; kx < 5; ++kx)
#pragma unroll
                    for (int cc = 0; cc < 8; ++cc)
                        acc1[cc] = fmaf(row[cc + kx], w[(r - 1) * 5 + kx], acc1[cc]);
            }
        }
        float bsum = s_b1[o];
#pragma unroll
        for (int j = 0; j < 4; ++j) {
            float m = fmaxf(fmaxf(acc0[2*j], acc0[2*j+1]), fmaxf(acc1[2*j], acc1[2*j+1]));
            s_p1[inst * 864 + o * 144 + py * 12 + g * 4 + j] = fmaxf(m + bsum, 0.f);
        }
    }
    __syncthreads();

    // ---- conv2 5x5 (6->16) + pool2x2 + relu : 512 tasks = 2 full rounds ----
    for (int t = tid; t < 512; t += 256) {
        int o    = t & 15; int u = t >> 4;
        int inst = u & 3;  int pp = u >> 2;
        int py   = pp >> 1, pxp = pp & 1;

        float acc0[4], acc1[4];
#pragma unroll
        for (int i = 0; i < 4; ++i) { acc0[i] = 0.f; acc1[i] = 0.f; }

        const float* pbase = &s_p1[inst * 864 + (py * 2) * 12 + pxp * 4];

        for (int ic = 0; ic < 6; ++ic) {
            float w[25];
#pragma unroll
            for (int k = 0; k < 25; ++k) w[k] = s_w2t[(ic * 25 + k) * 16 + o];
            const float* prow = pbase + ic * 144;
#pragma unroll
            for (int r = 0; r < 6; ++r) {
                const float4* rp = (const float4*)(prow + r * 12);  // 16B aligned
                float4 q0 = rp[0], q1 = rp[1];
                float row[8] = {q0.x,q0.y,q0.z,q0.w,q1.x,q1.y,q1.z,q1.w};
                if (r <= 4) {
#pragma unroll
                    for (int kx = 0; kx < 5; ++kx)
#pragma unroll
                        for (int cc = 0; cc < 4; ++cc)
                            acc0[cc] = fmaf(row[cc + kx], w[r * 5 + kx], acc0[cc]);
                }
                if (r >= 1) {
#pragma unroll
                    for (int kx = 0; kx < 5; ++kx)
#pragma unroll
                        for (int cc = 0; cc < 4; ++cc)
                            acc1[cc] = fmaf(row[cc + kx], w[(r - 1) * 5 + kx], acc1[cc]);
                }
            }
        }
        float bsum = s_b2[o];
#pragma unroll
        for (int j = 0; j < 2; ++j) {
            float m = fmaxf(fmaxf(acc0[2*j], acc0[2*j+1]), fmaxf(acc1[2*j], acc1[2*j+1]));
            s_p2[inst * 256 + o * 16 + py * 4 + (pxp * 2 + j)] = fmaxf(m + bsum, 0.f);
        }
    }
    __syncthreads();

    // ---- fc1: 256 -> 120, relu. One lane per output row, all 4 instances ----
    // LDS activation reads are wave-identical addresses -> pure broadcast.
    if (tid < 120) {
        const float4* wr = (const float4*)(fw1 + tid * 256);
        const float4* q0 = (const float4*)(s_p2);
        const float4* q1 = (const float4*)(s_p2 + 256);
        const float4* q2 = (const float4*)(s_p2 + 512);
        const float4* q3 = (const float4*)(s_p2 + 768);
        float a0 = 0.f, a1 = 0.f, a2 = 0.f, a3 = 0.f;
#pragma unroll 4
        for (int k = 0; k < 64; ++k) {
            float4 w4 = wr[k];
            float4 p;
            p = q0[k]; a0 = fmaf(w4.x,p.x,a0); a0 = fmaf(w4.y,p.y,a0); a0 = fmaf(w4.z,p.z,a0); a0 = fmaf(w4.w,p.w,a0);
            p = q1[k]; a1 = fmaf(w4.x,p.x,a1); a1 = fmaf(w4.y,p.y,a1); a1 = fmaf(w4.z,p.z,a1); a1 = fmaf(w4.w,p.w,a1);
            p = q2[k]; a2 = fmaf(w4.x,p.x,a2); a2 = fmaf(w4.y,p.y,a2); a2 = fmaf(w4.z,p.z,a2); a2 = fmaf(w4.w,p.w,a2);
            p = q3[k]; a3 = fmaf(w4.x,p.x,a3); a3 = fmaf(w4.y,p.y,a3); a3 = fmaf(w4.z,p.z,a3); a3 = fmaf(w4.w,p.w,a3);
        }
        float bb = fb1[tid];
        s_f1[0 * 120 + tid] = fmaxf(a0 + bb, 0.f);
        s_f1[1 * 120 + tid] = fmaxf(a1 + bb, 0.f);
        s_f1[2 * 120 + tid] = fmaxf(a2 + bb, 0.f);
        s_f1[3 * 120 + tid] = fmaxf(a3 + bb, 0.f);
    }
    __syncthreads();

    // ---- fc2: 120 -> 84, relu ----
    if (tid < 84) {
        const float4* wr = (const float4*)(fw2 + tid * 120);
        const float4* q0 = (const float4*)(s_f1);
        const float4* q1 = (const float4*)(s_f1 + 120);
        const float4* q2 = (const float4*)(s_f1 + 240);
        const float4* q3 = (const float4*)(s_f1 + 360);
        float a0 = 0.f, a1 = 0.f, a2 = 0.f, a3 = 0.f;
#pragma unroll 5
        for (int k = 0; k < 30; ++k) {
            float4 w4 = wr[k];
            float4 p;
            p = q0[k]; a0 = fmaf(w4.x,p.x,a0); a0 = fmaf(w4.y,p.y,a0); a0 = fmaf(w4.z,p.z,a0); a0 = fmaf(w4.w,p.w,a0);
            p = q1[k]; a1 = fmaf(w4.x,p.x,a1); a1 = fmaf(w4.y,p.y,a1); a1 = fmaf(w4.z,p.z,a1); a1 = fmaf(w4.w,p.w,a1);
            p = q2[k]; a2 = fmaf(w4.x,p.x,a2); a2 = fmaf(w4.y,p.y,a2); a2 = fmaf(w4.z,p.z,a2); a2 = fmaf(w4.w,p.w,a2);
            p = q3[k]; a3 = fmaf(w4.x,p.x,a3); a3 = fmaf(w4.y,p.y,a3); a3 = fmaf(w4.w,p.w,a3); a3 = fmaf(w4.z,p.z,a3);
        }
        float bb = fb2[tid];
        s_f2[0 * 84 + tid] = fmaxf(a0 + bb, 0.f);
        s_f2[1 * 84 + tid] = fmaxf(a1 + bb, 0.f);
        s_f2[2 * 84 + tid] = fmaxf(a2 + bb, 0.f);
        s_f2[3 * 84 + tid] = fmaxf(a3 + bb, 0.f);
    }
    __syncthreads();

    // ---- fc3: 84 -> 10 ----
    if (tid < 10) {
        const float4* wr = (const float4*)(fw3 + tid * 84);
        const float4* q0 = (const float4*)(s_f2);
        const float4* q1 = (const float4*)(s_f2 + 84);
        const float4* q2 = (const float4*)(s_f2 + 168);
        const float4* q3 = (const float4*)(s_f2 + 252);
        float a0 = 0.f, a1 = 0.f, a2 = 0.f, a3 = 0.f;
#pragma unroll
        for (int k = 0; k < 21; ++k) {
            float4 w4 = wr[k];
            float4 p;
            p = q0[k]; a0 = fmaf(w4.x,p.x,a0); a0 = fmaf(w4.y,p.y,a0); a0 = fmaf(w4.z,p.z,a0); a0 = fmaf(w4.w,p.w,a0);
            p = q1[k]; a1 = fmaf(w4.x,p.x,a1); a1 = fmaf(w4.y,p.y,a1); a1 = fmaf(w4.z,p.z,a1); a1 = fmaf(w4.w,p.w,a1);
            p = q2[k]; a2 = fmaf(w4.x,p.x,a2); a2 = fmaf(w4.y,p.y,a2); a2 = fmaf(w4.z,p.z,a2); a2 = fmaf(w4.w,p.w,a2);
            p = q3[k]; a3 = fmaf(w4.x,p.x,a3); a3 = fmaf(w4.y,p.y,a3); a3 = fmaf(w4.z,p.z,a3); a3 = fmaf(w4.w,p.w,a3);
        }
        float bb = fb3[tid];
        s_log[0 * 10 + tid] = a0 + bb;
        s_log[1 * 10 + tid] = a1 + bb;
        s_log[2 * 10 + tid] = a2 + bb;
        s_log[3 * 10 + tid] = a3 + bb;
    }
    __syncthreads();

    // ---- softmax per instance (4 lanes) ----
    if (tid < 4) {
        const float* lg = &s_log[tid * 10];
        float mx = lg[0];
#pragma unroll
        for (int j = 1; j < 10; ++j) mx = fmaxf(mx, lg[j]);
        float e[10], sum = 0.f;
#pragma unroll
        for (int j = 0; j < 10; ++j) { e[j] = __expf(lg[j] - mx); sum += e[j]; }
        float inv = 1.f / sum;
#pragma unroll
        for (int j = 0; j < 10; ++j) s_prob[tid * 10 + j] = e[j] * inv;
    }
    __syncthreads();

    // ---- full convolution (len 19) + log, per sample ----
    if (tid < 19 * SPB) {
        int ls = tid / 19;         // local sample
        int t  = tid % 19;
        const float* pa = &s_prob[(ls * 2 + 0) * 10];
        const float* pb = &s_prob[(ls * 2 + 1) * 10];
        int jlo = t - 9 > 0 ? t - 9 : 0;
        int jhi = t < 9 ? t : 9;
        float z = 0.f;
        for (int j = jlo; j <= jhi; ++j)
            z += pa[j] * pb[t - j];
        out[(size_t)(b0 + ls) * 19 + t] = __logf(z);
    }
}

extern "C" void kernel_launch(void* const* d_in, const int* in_sizes, int n_in,
                              void* d_out, int out_size, void* d_ws, size_t ws_size,
                              hipStream_t stream) {
    const float* x   = (const float*)d_in[0];
    const float* cw1 = (const float*)d_in[1];
    const float* cb1 = (const float*)d_in[2];
    const float* cw2 = (const float*)d_in[3];
    const float* cb2 = (const float*)d_in[4];
    const float* fw1 = (const float*)d_in[5];
    const float* fb1 = (const float*)d_in[6];
    const float* fw2 = (const float*)d_in[7];
    const float* fb2 = (const float*)d_in[8];
    const float* fw3 = (const float*)d_in[9];
    const float* fb3 = (const float*)d_in[10];
    float* out = (float*)d_out;

    const int B = in_sizes[0] / (2 * 28 * 28);   // 16384

    lenet_fused<<<B / SPB, 256, 0, stream>>>(x, cw1, cb1, cw2, cb2,
                                             fw1, fb1, fw2, fb2, fw3, fb3, out);
}

// Round 4
// 570.375 us; speedup vs baseline: 1.5142x; 1.0036x over previous
//
#include <hip/hip_runtime.h>
#include <math.h>

// Fused dual-LeNet + len-19 full convolution + log.
// 2 samples (4 LeNet instances) per block, 256 threads.
// Conv weights staged in LDS (transposed, conflict-free broadcast reads).
// amdgpu_waves_per_eu(4,4) pins occupancy at 4 waves/EU -> 128-VGPR budget,
// preventing the backend from squeezing to 64 VGPRs and spilling to scratch
// (round 3: 917 MB of spill traffic at VGPR_Count=64).

#define SPB 2   // samples per block

__global__ __launch_bounds__(256) __attribute__((amdgpu_waves_per_eu(4, 4)))
void lenet_fused(
    const float* __restrict__ x,     // [B,2,28,28]
    const float* __restrict__ cw1,   // [6,1,5,5]
    const float* __restrict__ cb1,   // [6]
    const float* __restrict__ cw2,   // [16,6,5,5]
    const float* __restrict__ cb2,   // [16]
    const float* __restrict__ fw1,   // [120,256]
    const float* __restrict__ fb1,   // [120]
    const float* __restrict__ fw2,   // [84,120]
    const float* __restrict__ fb2,   // [84]
    const float* __restrict__ fw3,   // [10,84]
    const float* __restrict__ fb3,   // [10]
    float* __restrict__ out)         // [B,19]
{
    const int tid = threadIdx.x;
    const int b0  = blockIdx.x * SPB;

    __shared__ __align__(16) float s_pool[4 * 784];      // images; reused post-conv1
    __shared__ __align__(16) float s_p1  [4 * 864];      // [inst][6][12][12]
    __shared__ __align__(16) float s_w1t [25 * 8];       // conv1 W^T [k][o]
    __shared__ float s_b1[8];
    __shared__ __align__(16) float s_w2t [150 * 16];     // conv2 W^T [ic*25+k][o]
    __shared__ float s_b2[16];

    float* s_img  = s_pool;          // 3136 floats (4 inst x 784)
    float* s_p2   = s_pool;          // 1024
    float* s_f1   = s_pool + 1024;   // 480
    float* s_f2   = s_pool + 1504;   // 336
    float* s_log  = s_pool + 1840;   // 40
    float* s_prob = s_pool + 1880;   // 40

    // ---- stage images + conv weights ----
    {
        const float4* xb = (const float4*)(x + (size_t)b0 * 1568);
        float4* si = (float4*)s_img;
        for (int i = tid; i < 392 * SPB; i += 256) si[i] = xb[i];
    }
    for (int i = tid; i < 150; i += 256) {          // cw1 -> [k][o] (stride 8)
        int o = i / 25, k = i % 25;
        s_w1t[k * 8 + o] = cw1[i];
    }
    for (int i = tid; i < 2400; i += 256) {         // cw2 -> [ic*25+k][o] (stride 16)
        int o = i / 150, r = i % 150;
        s_w2t[r * 16 + o] = cw2[i];
    }
    if (tid < 6)  s_b1[tid] = cb1[tid];
    if (tid < 16) s_b2[tid] = cb2[tid];
    __syncthreads();

    // ---- conv1 5x5 (1->6) + pool2x2 + relu : 864 tasks ----
    for (int t = tid; t < 864; t += 256) {
        int o  = t % 6;  int u = t / 6;
        int g  = u % 3;  u /= 3;
        int py = u % 12; int inst = u / 12;

        float w[25];
#pragma unroll
        for (int k = 0; k < 25; ++k) w[k] = s_w1t[k * 8 + o];

        float acc0[8], acc1[8];
#pragma unroll
        for (int i = 0; i < 8; ++i) { acc0[i] = 0.f; acc1[i] = 0.f; }

        const float* srow = &s_img[inst * 784 + (py * 2) * 28 + g * 8];
#pragma unroll
        for (int r = 0; r < 6; ++r) {
            const float4* rp = (const float4*)(srow + r * 28);  // 16B aligned
            float4 q0 = rp[0], q1 = rp[1], q2 = rp[2];
            float row[12] = {q0.x,q0.y,q0.z,q0.w,q1.x,q1.y,q1.z,q1.w,q2.x,q2.y,q2.z,q2.w};
            if (r <= 4) {
#pragma unroll
                for (int kx = 0; kx < 5; ++kx)
#pragma unroll
                    for (int cc = 0; cc < 8; ++cc)
                        acc0[cc] = fmaf(row[cc + kx], w[r * 5 + kx], acc0[cc]);
            }
            if (r >= 1) {
#pragma unroll
                for (int kx = 0; kx < 5; ++kx)
#pragma unroll
                    for (int cc = 0; cc < 8; ++cc)
                        acc1[cc] = fmaf(row[cc + kx], w[(r - 1) * 5 + kx], acc1[cc]);
            }
        }
        float bsum = s_b1[o];
#pragma unroll
        for (int j = 0; j < 4; ++j) {
            float m = fmaxf(fmaxf(acc0[2*j], acc0[2*j+1]), fmaxf(acc1[2*j], acc1[2*j+1]));
            s_p1[inst * 864 + o * 144 + py * 12 + g * 4 + j] = fmaxf(m + bsum, 0.f);
        }
    }
    __syncthreads();

    // ---- conv2 5x5 (6->16) + pool2x2 + relu : 512 tasks = 2 full rounds ----
    for (int t = tid; t < 512; t += 256) {
        int o    = t & 15; int u = t >> 4;
        int inst = u & 3;  int pp = u >> 2;
        int py   = pp >> 1, pxp = pp & 1;

        float acc0[4], acc1[4];
#pragma unroll
        for (int i = 0; i < 4; ++i) { acc0[i] = 0.f; acc1[i] = 0.f; }

        const float* pbase = &s_p1[inst * 864 + (py * 2) * 12 + pxp * 4];

        for (int ic = 0; ic < 6; ++ic) {
            float w[25];
#pragma unroll
            for (int k = 0; k < 25; ++k) w[k] = s_w2t[(ic * 25 + k) * 16 + o];
            const float* prow = pbase + ic * 144;
#pragma unroll
            for (int r = 0; r < 6; ++r) {
                const float4* rp = (const float4*)(prow + r * 12);  // 16B aligned
                float4 q0 = rp[0], q1 = rp[1];
                float row[8] = {q0.x,q0.y,q0.z,q0.w,q1.x,q1.y,q1.z,q1.w};
                if (r <= 4) {
#pragma unroll
                    for (int kx = 0; kx < 5; ++kx)
#pragma unroll
                        for (int cc = 0; cc < 4; ++cc)
                            acc0[cc] = fmaf(row[cc + kx], w[r * 5 + kx], acc0[cc]);
                }
                if (r >= 1) {
#pragma unroll
                    for (int kx = 0; kx < 5; ++kx)
#pragma unroll
                        for (int cc = 0; cc < 4; ++cc)
                            acc1[cc] = fmaf(row[cc + kx], w[(r - 1) * 5 + kx], acc1[cc]);
                }
            }
        }
        float bsum = s_b2[o];
#pragma unroll
        for (int j = 0; j < 2; ++j) {
            float m = fmaxf(fmaxf(acc0[2*j], acc0[2*j+1]), fmaxf(acc1[2*j], acc1[2*j+1]));
            s_p2[inst * 256 + o * 16 + py * 4 + (pxp * 2 + j)] = fmaxf(m + bsum, 0.f);
        }
    }
    __syncthreads();

    // ---- fc1: 256 -> 120, relu. One lane per output row, all 4 instances ----
    if (tid < 120) {
        const float4* wr = (const float4*)(fw1 + tid * 256);
        const float4* q0 = (const float4*)(s_p2);
        const float4* q1 = (const float4*)(s_p2 + 256);
        const float4* q2 = (const float4*)(s_p2 + 512);
        const float4* q3 = (const float4*)(s_p2 + 768);
        float a0 = 0.f, a1 = 0.f, a2 = 0.f, a3 = 0.f;
#pragma unroll 4
        for (int k = 0; k < 64; ++k) {
            float4 w4 = wr[k];
            float4 p;
            p = q0[k]; a0 = fmaf(w4.x,p.x,a0); a0 = fmaf(w4.y,p.y,a0); a0 = fmaf(w4.z,p.z,a0); a0 = fmaf(w4.w,p.w,a0);
            p = q1[k]; a1 = fmaf(w4.x,p.x,a1); a1 = fmaf(w4.y,p.y,a1); a1 = fmaf(w4.z,p.z,a1); a1 = fmaf(w4.w,p.w,a1);
            p = q2[k]; a2 = fmaf(w4.x,p.x,a2); a2 = fmaf(w4.y,p.y,a2); a2 = fmaf(w4.z,p.z,a2); a2 = fmaf(w4.w,p.w,a2);
            p = q3[k]; a3 = fmaf(w4.x,p.x,a3); a3 = fmaf(w4.y,p.y,a3); a3 = fmaf(w4.z,p.z,a3); a3 = fmaf(w4.w,p.w,a3);
        }
        float bb = fb1[tid];
        s_f1[0 * 120 + tid] = fmaxf(a0 + bb, 0.f);
        s_f1[1 * 120 + tid] = fmaxf(a1 + bb, 0.f);
        s_f1[2 * 120 + tid] = fmaxf(a2 + bb, 0.f);
        s_f1[3 * 120 + tid] = fmaxf(a3 + bb, 0.f);
    }
    __syncthreads();

    // ---- fc2: 120 -> 84, relu ----
    if (tid < 84) {
        const float4* wr = (const float4*)(fw2 + tid * 120);
        const float4* q0 = (const float4*)(s_f1);
        const float4* q1 = (const float4*)(s_f1 + 120);
        const float4* q2 = (const float4*)(s_f1 + 240);
        const float4* q3 = (const float4*)(s_f1 + 360);
        float a0 = 0.f, a1 = 0.f, a2 = 0.f, a3 = 0.f;
#pragma unroll 5
        for (int k = 0; k < 30; ++k) {
            float4 w4 = wr[k];
            float4 p;
            p = q0[k]; a0 = fmaf(w4.x,p.x,a0); a0 = fmaf(w4.y,p.y,a0); a0 = fmaf(w4.z,p.z,a0); a0 = fmaf(w4.w,p.w,a0);
            p = q1[k]; a1 = fmaf(w4.x,p.x,a1); a1 = fmaf(w4.y,p.y,a1); a1 = fmaf(w4.z,p.z,a1); a1 = fmaf(w4.w,p.w,a1);
            p = q2[k]; a2 = fmaf(w4.x,p.x,a2); a2 = fmaf(w4.y,p.y,a2); a2 = fmaf(w4.z,p.z,a2); a2 = fmaf(w4.w,p.w,a2);
            p = q3[k]; a3 = fmaf(w4.x,p.x,a3); a3 = fmaf(w4.y,p.y,a3); a3 = fmaf(w4.z,p.z,a3); a3 = fmaf(w4.w,p.w,a3);
        }
        float bb = fb2[tid];
        s_f2[0 * 84 + tid] = fmaxf(a0 + bb, 0.f);
        s_f2[1 * 84 + tid] = fmaxf(a1 + bb, 0.f);
        s_f2[2 * 84 + tid] = fmaxf(a2 + bb, 0.f);
        s_f2[3 * 84 + tid] = fmaxf(a3 + bb, 0.f);
    }
    __syncthreads();

    // ---- fc3: 84 -> 10 ----
    if (tid < 10) {
        const float4* wr = (const float4*)(fw3 + tid * 84);
        const float4* q0 = (const float4*)(s_f2);
        const float4* q1 = (const float4*)(s_f2 + 84);
        const float4* q2 = (const float4*)(s_f2 + 168);
        const float4* q3 = (const float4*)(s_f2 + 252);
        float a0 = 0.f, a1 = 0.f, a2 = 0.f, a3 = 0.f;
#pragma unroll
        for (int k = 0; k < 21; ++k) {
            float4 w4 = wr[k];
            float4 p;
            p = q0[k]; a0 = fmaf(w4.x,p.x,a0); a0 = fmaf(w4.y,p.y,a0); a0 = fmaf(w4.z,p.z,a0); a0 = fmaf(w4.w,p.w,a0);
            p = q1[k]; a1 = fmaf(w4.x,p.x,a1); a1 = fmaf(w4.y,p.y,a1); a1 = fmaf(w4.z,p.z,a1); a1 = fmaf(w4.w,p.w,a1);
            p = q2[k]; a2 = fmaf(w4.x,p.x,a2); a2 = fmaf(w4.y,p.y,a2); a2 = fmaf(w4.z,p.z,a2); a2 = fmaf(w4.w,p.w,a2);
            p = q3[k]; a3 = fmaf(w4.x,p.x,a3); a3 = fmaf(w4.y,p.y,a3); a3 = fmaf(w4.z,p.z,a3); a3 = fmaf(w4.w,p.w,a3);
        }
        float bb = fb3[tid];
        s_log[0 * 10 + tid] = a0 + bb;
        s_log[1 * 10 + tid] = a1 + bb;
        s_log[2 * 10 + tid] = a2 + bb;
        s_log[3 * 10 + tid] = a3 + bb;
    }
    __syncthreads();

    // ---- softmax per instance (4 lanes) ----
    if (tid < 4) {
        const float* lg = &s_log[tid * 10];
        float mx = lg[0];
#pragma unroll
        for (int j = 1; j < 10; ++j) mx = fmaxf(mx, lg[j]);
        float e[10], sum = 0.f;
#pragma unroll
        for (int j = 0; j < 10; ++j) { e[j] = __expf(lg[j] - mx); sum += e[j]; }
        float inv = 1.f / sum;
#pragma unroll
        for (int j = 0; j < 10; ++j) s_prob[tid * 10 + j] = e[j] * inv;
    }
    __syncthreads();

    // ---- full convolution (len 19) + log, per sample ----
    if (tid < 19 * SPB) {
        int ls = tid / 19;         // local sample
        int t  = tid % 19;
        const float* pa = &s_prob[(ls * 2 + 0) * 10];
        const float* pb = &s_prob[(ls * 2 + 1) * 10];
        int jlo = t - 9 > 0 ? t - 9 : 0;
        int jhi = t < 9 ? t : 9;
        float z = 0.f;
        for (int j = jlo; j <= jhi; ++j)
            z += pa[j] * pb[t - j];
        out[(size_t)(b0 + ls) * 19 + t] = __logf(z);
    }
}

extern "C" void kernel_launch(void* const* d_in, const int* in_sizes, int n_in,
                              void* d_out, int out_size, void* d_ws, size_t ws_size,
                              hipStream_t stream) {
    const float* x   = (const float*)d_in[0];
    const float* cw1 = (const float*)d_in[1];
    const float* cb1 = (const float*)d_in[2];
    const float* cw2 = (const float*)d_in[3];
    const float* cb2 = (const float*)d_in[4];
    const float* fw1 = (const float*)d_in[5];
    const float* fb1 = (const float*)d_in[6];
    const float* fw2 = (const float*)d_in[7];
    const float* fb2 = (const float*)d_in[8];
    const float* fw3 = (const float*)d_in[9];
    const float* fb3 = (const float*)d_in[10];
    float* out = (float*)d_out;

    const int B = in_sizes[0] / (2 * 28 * 28);   // 16384

    lenet_fused<<<B / SPB, 256, 0, stream>>>(x, cw1, cb1, cw2, cb2,
                                             fw1, fb1, fw2, fb2, fw3, fb3, out);
}

// Round 5
// 495.594 us; speedup vs baseline: 1.7427x; 1.1509x over previous
//
#include <hip/hip_runtime.h>
#include <math.h>

// Fused dual-LeNet + len-19 full convolution + log.
// 2 samples (4 LeNet instances) per block, 256 threads.
// Round-5 design point: the backend pins VGPR_Count=64 regardless of
// launch_bounds/waves_per_eu hints (rounds 3-4: 917 MB scratch spill).
// So this version is engineered to FIT 64 VGPRs: conv weights are read
// from LDS at point of use (broadcast, conflict-free transposed layout),
// ky/ic loops are NOT unrolled (boundary rows peeled), keeping live state
// at ~35-40 floats. No spill expected.

#define SPB 2   // samples per block

__global__ __launch_bounds__(256) void lenet_fused(
    const float* __restrict__ x,     // [B,2,28,28]
    const float* __restrict__ cw1,   // [6,1,5,5]
    const float* __restrict__ cb1,   // [6]
    const float* __restrict__ cw2,   // [16,6,5,5]
    const float* __restrict__ cb2,   // [16]
    const float* __restrict__ fw1,   // [120,256]
    const float* __restrict__ fb1,   // [120]
    const float* __restrict__ fw2,   // [84,120]
    const float* __restrict__ fb2,   // [84]
    const float* __restrict__ fw3,   // [10,84]
    const float* __restrict__ fb3,   // [10]
    float* __restrict__ out)         // [B,19]
{
    const int tid = threadIdx.x;
    const int b0  = blockIdx.x * SPB;

    __shared__ __align__(16) float s_pool[4 * 784];      // images; reused post-conv1
    __shared__ __align__(16) float s_p1  [4 * 864];      // [inst][6][12][12]
    __shared__ __align__(16) float s_w1t [25 * 8];       // conv1 W^T [k][o], stride 8
    __shared__ float s_b1[8];
    __shared__ __align__(16) float s_w2t [150 * 16];     // conv2 W^T [ic*25+k][o], stride 16
    __shared__ float s_b2[16];

    float* s_img  = s_pool;          // 3136 floats (4 inst x 784)
    float* s_p2   = s_pool;          // 1024
    float* s_f1   = s_pool + 1024;   // 480
    float* s_f2   = s_pool + 1504;   // 336
    float* s_log  = s_pool + 1840;   // 40
    float* s_prob = s_pool + 1880;   // 40

    // ---- stage images + conv weights ----
    {
        const float4* xb = (const float4*)(x + (size_t)b0 * 1568);
        float4* si = (float4*)s_img;
        for (int i = tid; i < 392 * SPB; i += 256) si[i] = xb[i];
    }
    for (int i = tid; i < 150; i += 256) {          // cw1 -> [k][o]
        int o = i / 25, k = i % 25;
        s_w1t[k * 8 + o] = cw1[i];
    }
    for (int i = tid; i < 2400; i += 256) {         // cw2 -> [ic*25+k][o]
        int o = i / 150, r = i % 150;
        s_w2t[r * 16 + o] = cw2[i];
    }
    if (tid < 6)  s_b1[tid] = cb1[tid];
    if (tid < 16) s_b2[tid] = cb2[tid];
    __syncthreads();

    // ---- conv1 5x5 (1->6) + pool2x2 + relu : 864 tasks ----
    // o fastest -> within a wave the w-reads are broadcast groups.
#pragma unroll 1
    for (int t = tid; t < 864; t += 256) {
        int o  = t % 6;  int u = t / 6;
        int g  = u % 3;  u /= 3;
        int py = u % 12; int inst = u / 12;

        float acc0[8], acc1[8];
#pragma unroll
        for (int i = 0; i < 8; ++i) { acc0[i] = 0.f; acc1[i] = 0.f; }

        const float* srow = &s_img[inst * 784 + (py * 2) * 28 + g * 8];
        const float* wt   = &s_w1t[o];

        // r = 0 : window row 0 of acc0 only
        {
            const float4* rp = (const float4*)(srow);
            float4 q0 = rp[0], q1 = rp[1], q2 = rp[2];
            float row[12] = {q0.x,q0.y,q0.z,q0.w,q1.x,q1.y,q1.z,q1.w,q2.x,q2.y,q2.z,q2.w};
#pragma unroll
            for (int kx = 0; kx < 5; ++kx) {
                float wv = wt[kx * 8];
#pragma unroll
                for (int cc = 0; cc < 8; ++cc)
                    acc0[cc] = fmaf(row[cc + kx], wv, acc0[cc]);
            }
        }
        // r = 1..4 : both windows (NOT unrolled -> low register pressure)
#pragma unroll 1
        for (int r = 1; r <= 4; ++r) {
            const float4* rp = (const float4*)(srow + r * 28);
            float4 q0 = rp[0], q1 = rp[1], q2 = rp[2];
            float row[12] = {q0.x,q0.y,q0.z,q0.w,q1.x,q1.y,q1.z,q1.w,q2.x,q2.y,q2.z,q2.w};
            const float* whi = wt + r * 40;        // w row r     (acc0)
            const float* wlo = whi - 40;           // w row r-1   (acc1)
#pragma unroll
            for (int kx = 0; kx < 5; ++kx) {
                float wh = whi[kx * 8];
                float wl = wlo[kx * 8];
#pragma unroll
                for (int cc = 0; cc < 8; ++cc) {
                    acc0[cc] = fmaf(row[cc + kx], wh, acc0[cc]);
                    acc1[cc] = fmaf(row[cc + kx], wl, acc1[cc]);
                }
            }
        }
        // r = 5 : window row 4 of acc1 only
        {
            const float4* rp = (const float4*)(srow + 5 * 28);
            float4 q0 = rp[0], q1 = rp[1], q2 = rp[2];
            float row[12] = {q0.x,q0.y,q0.z,q0.w,q1.x,q1.y,q1.z,q1.w,q2.x,q2.y,q2.z,q2.w};
            const float* wlo = wt + 4 * 40;
#pragma unroll
            for (int kx = 0; kx < 5; ++kx) {
                float wl = wlo[kx * 8];
#pragma unroll
                for (int cc = 0; cc < 8; ++cc)
                    acc1[cc] = fmaf(row[cc + kx], wl, acc1[cc]);
            }
        }
        float bsum = s_b1[o];
#pragma unroll
        for (int j = 0; j < 4; ++j) {
            float m = fmaxf(fmaxf(acc0[2*j], acc0[2*j+1]), fmaxf(acc1[2*j], acc1[2*j+1]));
            s_p1[inst * 864 + o * 144 + py * 12 + g * 4 + j] = fmaxf(m + bsum, 0.f);
        }
    }
    __syncthreads();

    // ---- conv2 5x5 (6->16) + pool2x2 + relu : 512 tasks = 2 full rounds ----
#pragma unroll 1
    for (int t = tid; t < 512; t += 256) {
        int o    = t & 15; int u = t >> 4;
        int inst = u & 3;  int pp = u >> 2;
        int py   = pp >> 1, pxp = pp & 1;

        float acc0[4], acc1[4];
#pragma unroll
        for (int i = 0; i < 4; ++i) { acc0[i] = 0.f; acc1[i] = 0.f; }

        const float* pbase = &s_p1[inst * 864 + (py * 2) * 12 + pxp * 4];
        const float* wt    = &s_w2t[o];

#pragma unroll 1
        for (int ic = 0; ic < 6; ++ic) {
            const float* prow = pbase + ic * 144;
            const float* wic  = wt + ic * 400;     // (ic*25)*16 + o

            // r = 0
            {
                const float4* rp = (const float4*)(prow);
                float4 q0 = rp[0], q1 = rp[1];
                float row[8] = {q0.x,q0.y,q0.z,q0.w,q1.x,q1.y,q1.z,q1.w};
#pragma unroll
                for (int kx = 0; kx < 5; ++kx) {
                    float wv = wic[kx * 16];
#pragma unroll
                    for (int cc = 0; cc < 4; ++cc)
                        acc0[cc] = fmaf(row[cc + kx], wv, acc0[cc]);
                }
            }
            // r = 1..4
#pragma unroll 1
            for (int r = 1; r <= 4; ++r) {
                const float4* rp = (const float4*)(prow + r * 12);
                float4 q0 = rp[0], q1 = rp[1];
                float row[8] = {q0.x,q0.y,q0.z,q0.w,q1.x,q1.y,q1.z,q1.w};
                const float* whi = wic + r * 80;   // w row r    (acc0)
                const float* wlo = whi - 80;       // w row r-1  (acc1)
#pragma unroll
                for (int kx = 0; kx < 5; ++kx) {
                    float wh = whi[kx * 16];
                    float wl = wlo[kx * 16];
#pragma unroll
                    for (int cc = 0; cc < 4; ++cc) {
                        acc0[cc] = fmaf(row[cc + kx], wh, acc0[cc]);
                        acc1[cc] = fmaf(row[cc + kx], wl, acc1[cc]);
                    }
                }
            }
            // r = 5
            {
                const float4* rp = (const float4*)(prow + 5 * 12);
                float4 q0 = rp[0], q1 = rp[1];
                float row[8] = {q0.x,q0.y,q0.z,q0.w,q1.x,q1.y,q1.z,q1.w};
                const float* wlo = wic + 4 * 80;
#pragma unroll
                for (int kx = 0; kx < 5; ++kx) {
                    float wl = wlo[kx * 16];
#pragma unroll
                    for (int cc = 0; cc < 4; ++cc)
                        acc1[cc] = fmaf(row[cc + kx], wl, acc1[cc]);
                }
            }
        }
        float bsum = s_b2[o];
#pragma unroll
        for (int j = 0; j < 2; ++j) {
            float m = fmaxf(fmaxf(acc0[2*j], acc0[2*j+1]), fmaxf(acc1[2*j], acc1[2*j+1]));
            s_p2[inst * 256 + o * 16 + py * 4 + (pxp * 2 + j)] = fmaxf(m + bsum, 0.f);
        }
    }
    __syncthreads();

    // ---- fc1: 256 -> 120, relu. 240 lanes, 2 instances each ----
    if (tid < 240) {
        int o  = tid % 120;
        int pr = tid / 120;                  // instance pair 0 -> {0,1}, 1 -> {2,3}
        const float4* wr = (const float4*)(fw1 + o * 256);
        const float4* q0 = (const float4*)(s_p2 + (2 * pr    ) * 256);
        const float4* q1 = (const float4*)(s_p2 + (2 * pr + 1) * 256);
        float a0 = 0.f, a1 = 0.f;
#pragma unroll 4
        for (int k = 0; k < 64; ++k) {
            float4 w4 = wr[k];
            float4 p;
            p = q0[k]; a0 = fmaf(w4.x,p.x,a0); a0 = fmaf(w4.y,p.y,a0); a0 = fmaf(w4.z,p.z,a0); a0 = fmaf(w4.w,p.w,a0);
            p = q1[k]; a1 = fmaf(w4.x,p.x,a1); a1 = fmaf(w4.y,p.y,a1); a1 = fmaf(w4.z,p.z,a1); a1 = fmaf(w4.w,p.w,a1);
        }
        float bb = fb1[o];
        s_f1[(2 * pr    ) * 120 + o] = fmaxf(a0 + bb, 0.f);
        s_f1[(2 * pr + 1) * 120 + o] = fmaxf(a1 + bb, 0.f);
    }
    __syncthreads();

    // ---- fc2: 120 -> 84, relu. 168 lanes, 2 instances each ----
    if (tid < 168) {
        int o  = tid % 84;
        int pr = tid / 84;
        const float4* wr = (const float4*)(fw2 + o * 120);
        const float4* q0 = (const float4*)(s_f1 + (2 * pr    ) * 120);
        const float4* q1 = (const float4*)(s_f1 + (2 * pr + 1) * 120);
        float a0 = 0.f, a1 = 0.f;
#pragma unroll 5
        for (int k = 0; k < 30; ++k) {
            float4 w4 = wr[k];
            float4 p;
            p = q0[k]; a0 = fmaf(w4.x,p.x,a0); a0 = fmaf(w4.y,p.y,a0); a0 = fmaf(w4.z,p.z,a0); a0 = fmaf(w4.w,p.w,a0);
            p = q1[k]; a1 = fmaf(w4.x,p.x,a1); a1 = fmaf(w4.y,p.y,a1); a1 = fmaf(w4.z,p.z,a1); a1 = fmaf(w4.w,p.w,a1);
        }
        float bb = fb2[o];
        s_f2[(2 * pr    ) * 84 + o] = fmaxf(a0 + bb, 0.f);
        s_f2[(2 * pr + 1) * 84 + o] = fmaxf(a1 + bb, 0.f);
    }
    __syncthreads();

    // ---- fc3: 84 -> 10. 40 lanes, 1 instance each ----
    if (tid < 40) {
        int o    = tid % 10;
        int inst = tid / 10;
        const float4* wr = (const float4*)(fw3 + o * 84);
        const float4* q0 = (const float4*)(s_f2 + inst * 84);
        float a0 = 0.f;
#pragma unroll
        for (int k = 0; k < 21; ++k) {
            float4 w4 = wr[k];
            float4 p = q0[k];
            a0 = fmaf(w4.x,p.x,a0); a0 = fmaf(w4.y,p.y,a0); a0 = fmaf(w4.z,p.z,a0); a0 = fmaf(w4.w,p.w,a0);
        }
        s_log[inst * 10 + o] = a0 + fb3[o];
    }
    __syncthreads();

    // ---- softmax per instance (4 lanes) ----
    if (tid < 4) {
        const float* lg = &s_log[tid * 10];
        float mx = lg[0];
#pragma unroll
        for (int j = 1; j < 10; ++j) mx = fmaxf(mx, lg[j]);
        float e[10], sum = 0.f;
#pragma unroll
        for (int j = 0; j < 10; ++j) { e[j] = __expf(lg[j] - mx); sum += e[j]; }
        float inv = 1.f / sum;
#pragma unroll
        for (int j = 0; j < 10; ++j) s_prob[tid * 10 + j] = e[j] * inv;
    }
    __syncthreads();

    // ---- full convolution (len 19) + log, per sample ----
    if (tid < 19 * SPB) {
        int ls = tid / 19;
        int t  = tid % 19;
        const float* pa = &s_prob[(ls * 2 + 0) * 10];
        const float* pb = &s_prob[(ls * 2 + 1) * 10];
        int jlo = t - 9 > 0 ? t - 9 : 0;
        int jhi = t < 9 ? t : 9;
        float z = 0.f;
        for (int j = jlo; j <= jhi; ++j)
            z += pa[j] * pb[t - j];
        out[(size_t)(b0 + ls) * 19 + t] = __logf(z);
    }
}

extern "C" void kernel_launch(void* const* d_in, const int* in_sizes, int n_in,
                              void* d_out, int out_size, void* d_ws, size_t ws_size,
                              hipStream_t stream) {
    const float* x   = (const float*)d_in[0];
    const float* cw1 = (const float*)d_in[1];
    const float* cb1 = (const float*)d_in[2];
    const float* cw2 = (const float*)d_in[3];
    const float* cb2 = (const float*)d_in[4];
    const float* fw1 = (const float*)d_in[5];
    const float* fb1 = (const float*)d_in[6];
    const float* fw2 = (const float*)d_in[7];
    const float* fb2 = (const float*)d_in[8];
    const float* fw3 = (const float*)d_in[9];
    const float* fb3 = (const float*)d_in[10];
    float* out = (float*)d_out;

    const int B = in_sizes[0] / (2 * 28 * 28);   // 16384

    lenet_fused<<<B / SPB, 256, 0, stream>>>(x, cw1, cb1, cw2, cb2,
                                             fw1, fb1, fw2, fb2, fw3, fb3, out);
}